// Round 3
// baseline (274.945 us; speedup 1.0000x reference)
//
#include <hip/hip_runtime.h>

#define Bn 8
#define Cn 512
#define Hn 8
#define Dn 64
#define Nn 1024
#define SCALEQ 0.125f

typedef unsigned short u16;
typedef unsigned short u16x8 __attribute__((ext_vector_type(8)));
typedef unsigned short u16x4 __attribute__((ext_vector_type(4)));
typedef short s16x4 __attribute__((ext_vector_type(4)));
typedef float f32x4 __attribute__((ext_vector_type(4)));
typedef __bf16 bf16x8 __attribute__((ext_vector_type(8)));

__device__ __forceinline__ u16 f2bf(float f){
  unsigned u = __float_as_uint(f);
  u += 0x7fffu + ((u >> 16) & 1u);   // RNE
  return (u16)(u >> 16);
}
__device__ __forceinline__ float bf2f(u16 h){
  return __uint_as_float(((unsigned)h) << 16);
}
__device__ __forceinline__ f32x4 mfma16(u16x8 a, u16x8 b, f32x4 c){
  return __builtin_amdgcn_mfma_f32_16x16x32_bf16(
      __builtin_bit_cast(bf16x8, a), __builtin_bit_cast(bf16x8, b), c, 0, 0, 0);
}
// K=16 variant: A/B layout (lane r,g holds k=4g+j) == 16x16 C/D layout (row=4g+rr) -> P stays in regs
__device__ __forceinline__ f32x4 mfma16k16(u16x4 a, u16x4 b, f32x4 c){
  return __builtin_amdgcn_mfma_f32_16x16x16bf16_1k(
      __builtin_bit_cast(s16x4, a), __builtin_bit_cast(s16x4, b), c, 0, 0, 0);
}

// ---------------- pre-pass: f32 -> bf16 weight convert ----------------
__global__ __launch_bounds__(256) void k_convert(const float* __restrict__ src,
                                                 u16* __restrict__ dst, int n4){
  int i = blockIdx.x * 256 + threadIdx.x;
  if (i >= n4) return;
  float4 f = reinterpret_cast<const float4*>(src)[i];
  u16x4 o;
  o[0] = f2bf(f.x); o[1] = f2bf(f.y); o[2] = f2bf(f.z); o[3] = f2bf(f.w);
  reinterpret_cast<u16x4*>(dst)[i] = o;
}

// ---------------- pre-pass: fmap [B][C][N] f32 -> fmapT [B][N][C] bf16 ----------------
__global__ __launch_bounds__(256) void k_transpose(const float* __restrict__ fmap,
                                                   u16* __restrict__ fmapT){
  __shared__ float tile[32][33];
  const int n0 = blockIdx.x * 32, c0 = blockIdx.y * 32, b = blockIdx.z;
  const int tx = threadIdx.x & 31, ty = threadIdx.x >> 5;   // 32 x 8
  const float* src = fmap + ((size_t)b * Cn + c0) * Nn + n0;
#pragma unroll
  for (int i = 0; i < 4; i++) tile[ty + 8*i][tx] = src[(size_t)(ty + 8*i) * Nn + tx];
  __syncthreads();
  u16* dst = fmapT + ((size_t)b * Nn + n0) * Cn + c0;
#pragma unroll
  for (int i = 0; i < 4; i++) dst[(size_t)(ty + 8*i) * Cn + tx] = f2bf(tile[tx][ty + 8*i]);
}

// ---------------- shared NT GEMM core: D[i][j] = sum_k A[i*lda+k] * B[j*ldb+k] ----------------
__device__ __forceinline__ void gemm_nt_64x64(const u16* __restrict__ Ap, int lda,
                                              const u16* __restrict__ Bp, int ldb,
                                              int K, f32x4 acc[4][4]){
  const int lane = threadIdx.x & 63;
  const int r = lane & 15, g = lane >> 4;
  const u16* pa = Ap + (size_t)r * lda + 8 * g;
  const u16* pb = Bp + (size_t)r * ldb + 8 * g;
  for (int kc = 0; kc < K; kc += 32){
    u16x8 af[4], bf[4];
#pragma unroll
    for (int t = 0; t < 4; t++) af[t] = *reinterpret_cast<const u16x8*>(pa + (size_t)t*16*lda + kc);
#pragma unroll
    for (int t = 0; t < 4; t++) bf[t] = *reinterpret_cast<const u16x8*>(pb + (size_t)t*16*ldb + kc);
#pragma unroll
    for (int i = 0; i < 4; i++)
#pragma unroll
      for (int j = 0; j < 4; j++)
        acc[i][j] = mfma16(af[i], bf[j], acc[i][j]);
  }
}

// ---------------- GEMM1: qkvL = Wqkvl @ fmap  (per batch) ----------------
__global__ __launch_bounds__(256) void k_gemm1(const u16* __restrict__ fmapT, // [B][N][C]
                                               const u16* __restrict__ W1,    // [2048][C]
                                               u16* __restrict__ Qb, u16* __restrict__ Kb,
                                               u16* __restrict__ Vt, u16* __restrict__ Lb){
  const int ob = blockIdx.x;           // 16 o-blocks of 128
  const int nb = blockIdx.y;           // 8 n-blocks of 128
  const int b  = blockIdx.z;
  const int w = threadIdx.x >> 6, wi = w >> 1, wj = w & 1;
  const int lane = threadIdx.x & 63, r = lane & 15, g = lane >> 4;
  const int seg = ob >> 2;             // 0=Q 1=K 2=V 3=L

  f32x4 acc[4][4];
  const f32x4 z = {0.f, 0.f, 0.f, 0.f};
#pragma unroll
  for (int i = 0; i < 4; i++)
#pragma unroll
    for (int j = 0; j < 4; j++) acc[i][j] = z;

  const u16* fbase = fmapT + (size_t)b * Nn * Cn;

  if (seg != 2){
    const u16* Ap = fbase + (size_t)(nb*128 + wi*64) * Cn;
    const u16* Bp = W1 + (size_t)(ob*128 + wj*64) * Cn;
    gemm_nt_64x64(Ap, Cn, Bp, Cn, Cn, acc);
    u16* dst = (seg == 0) ? Qb : (seg == 1 ? Kb : Lb);
    const float sc = (seg == 0) ? SCALEQ : 1.0f;
#pragma unroll
    for (int it = 0; it < 4; it++)
#pragma unroll
      for (int jt = 0; jt < 4; jt++)
#pragma unroll
        for (int rr = 0; rr < 4; rr++){
          int n = nb*128 + wi*64 + it*16 + 4*g + rr;
          int o = ob*128 + wj*64 + jt*16 + r;
          dst[((size_t)b * Nn + n) * Cn + (o & 511)] = f2bf(acc[it][jt][rr] * sc);
        }
  } else {
    const u16* Ap = W1 + (size_t)(ob*128 + wi*64) * Cn;
    const u16* Bp = fbase + (size_t)(nb*128 + wj*64) * Cn;
    gemm_nt_64x64(Ap, Cn, Bp, Cn, Cn, acc);
#pragma unroll
    for (int it = 0; it < 4; it++)
#pragma unroll
      for (int jt = 0; jt < 4; jt++)
#pragma unroll
        for (int rr = 0; rr < 4; rr++){
          int o = ob*128 + wi*64 + it*16 + 4*g + rr;
          int oo = o - 1024;
          int h = oo >> 6, d = oo & 63;
          int n = nb*128 + wj*64 + jt*16 + r;
          Vt[(((size_t)b * Hn + h) * Dn + d) * Nn + n] = f2bf(acc[it][jt][rr]);
        }
  }
}

// ---------------- attention: swapped flash, all-register P (no LDS, no barriers) -------------
// QK^T (x32): st[key 4g+rr][query r].  exp'd bf16 pack == B-frag of 16x16x16 MFMA (k=4g+j).
// PV (x16): accO[dt] = O^T[d = dt*16+4g+rr][query r].  Compiler free to pipeline K/V loads.
__global__ __launch_bounds__(256) void k_attn(const u16* __restrict__ Qb,  // [B][N][C] (pre-scaled)
                                              const u16* __restrict__ Kb,  // [B][N][C]
                                              const u16* __restrict__ Vt,  // [B][H][D][N]
                                              const u16* __restrict__ Lb,  // [B][N][C]
                                              u16* __restrict__ tok){      // [B][N][C]
  // XCD-bijective swizzle: the 16 q-blocks of one (b,h) share one XCD's L2
  const int bid = blockIdx.x;
  const int w0 = (bid & 7) * 128 + (bid >> 3);
  const int qblk = w0 & 15, h = (w0 >> 4) & 7, b = w0 >> 7;
  const int w = threadIdx.x >> 6, lane = threadIdx.x & 63;
  const int r = lane & 15, g = lane >> 4;
  const int q0 = qblk * 64 + w * 16;

  const u16* qrow = Qb + ((size_t)b * Nn + q0 + r) * Cn + h * Dn + 8 * g;
  u16x8 qf0 = *reinterpret_cast<const u16x8*>(qrow);
  u16x8 qf1 = *reinterpret_cast<const u16x8*>(qrow + 32);

  const u16* kbase = Kb + (size_t)b * Nn * Cn + h * Dn;
  const u16* vbase = Vt + ((size_t)b * Hn + h) * Dn * Nn;

  f32x4 accO[4];
  const f32x4 z = {0.f, 0.f, 0.f, 0.f};
#pragma unroll
  for (int dt = 0; dt < 4; dt++) accO[dt] = z;
  float m = -1e30f, lsum = 0.f;

  for (int kt = 0; kt < Nn; kt += 32){
    // QK^T: two 16-key tiles, K=32 over d
    const u16* kr0 = kbase + (size_t)(kt + r) * Cn + 8*g;
    const u16* kr1 = kbase + (size_t)(kt + 16 + r) * Cn + 8*g;
    u16x8 kf00 = *reinterpret_cast<const u16x8*>(kr0);
    u16x8 kf01 = *reinterpret_cast<const u16x8*>(kr0 + 32);
    u16x8 kf10 = *reinterpret_cast<const u16x8*>(kr1);
    u16x8 kf11 = *reinterpret_cast<const u16x8*>(kr1 + 32);
    f32x4 st0 = mfma16(kf00, qf0, z); st0 = mfma16(kf01, qf1, st0);
    f32x4 st1 = mfma16(kf10, qf0, z); st1 = mfma16(kf11, qf1, st1);

    // per-lane max over 8 scores + cross-g sync (2 shuffles)
    float tm = fmaxf(fmaxf(fmaxf(st0[0], st0[1]), fmaxf(st0[2], st0[3])),
                     fmaxf(fmaxf(st1[0], st1[1]), fmaxf(st1[2], st1[3])));
    tm = fmaxf(tm, __shfl_xor(tm, 16));
    tm = fmaxf(tm, __shfl_xor(tm, 32));
    // defer-max (T13): rescale only when max grew by > 8
    if (__any(tm - m > 8.f)){
      float mn = fmaxf(m, tm);
      float al = __expf(m - mn);
      m = mn;
      lsum *= al;
#pragma unroll
      for (int dt = 0; dt < 4; dt++) accO[dt] *= al;
    }
    // exp + pack into 16x16x16 B-fragments (layout already matches: k = 4g+j)
    u16x4 p0, p1;
    float ls = 0.f;
#pragma unroll
    for (int j = 0; j < 4; j++){
      float e0 = __expf(st0[j] - m);
      float e1 = __expf(st1[j] - m);
      ls += e0 + e1;
      p0[j] = f2bf(e0);
      p1[j] = f2bf(e1);
    }
    lsum += ls;
    // PV: 4 d-tiles x 2 key-tiles, V A-frags are 8B contiguous from Vt [d][n]
#pragma unroll
    for (int dt = 0; dt < 4; dt++){
      const u16* vr = vbase + (size_t)(dt*16 + r) * Nn + kt + 4*g;
      u16x4 vf0 = *reinterpret_cast<const u16x4*>(vr);
      u16x4 vf1 = *reinterpret_cast<const u16x4*>(vr + 16);
      accO[dt] = mfma16k16(vf0, p0, accO[dt]);
      accO[dt] = mfma16k16(vf1, p1, accO[dt]);
    }
  }

  // epilogue: cross-g lsum reduce, normalize, +L, write token-major bf16
  lsum += __shfl_xor(lsum, 16);
  lsum += __shfl_xor(lsum, 32);
  float linv = 1.0f / lsum;
  const int n = q0 + r;
  const u16* lrow = Lb + ((size_t)b * Nn + n) * Cn + h * Dn;
  u16* trow = tok + ((size_t)b * Nn + n) * Cn + h * Dn;
#pragma unroll
  for (int dt = 0; dt < 4; dt++){
    u16x4 lv = *reinterpret_cast<const u16x4*>(lrow + dt*16 + 4*g);
    u16x4 ov;
#pragma unroll
    for (int rr = 0; rr < 4; rr++)
      ov[rr] = f2bf(accO[dt][rr] * linv + bf2f(lv[rr]));
    *reinterpret_cast<u16x4*>(trow + dt*16 + 4*g) = ov;
  }
}

// ---------------- GEMM2: out = Wout @ tok + bout  -> f32 [B][C][N] ----------------
__global__ __launch_bounds__(256) void k_gemm2(const u16* __restrict__ tok, // [B][N][C]
                                               const u16* __restrict__ Wo,  // [C][C]
                                               const float* __restrict__ bout,
                                               float* __restrict__ out){
  const int ob = blockIdx.x;   // 4 o-blocks of 128
  const int nb = blockIdx.y;   // 8 n-blocks of 128
  const int b  = blockIdx.z;
  const int w = threadIdx.x >> 6, wi = w >> 1, wj = w & 1;
  const int lane = threadIdx.x & 63, r = lane & 15, g = lane >> 4;

  f32x4 acc[4][4];
  const f32x4 z = {0.f, 0.f, 0.f, 0.f};
#pragma unroll
  for (int i = 0; i < 4; i++)
#pragma unroll
    for (int j = 0; j < 4; j++) acc[i][j] = z;

  const u16* Ap = Wo + (size_t)(ob*128 + wi*64) * Cn;
  const u16* Bp = tok + (size_t)b * Nn * Cn + (size_t)(nb*128 + wj*64) * Cn;
  gemm_nt_64x64(Ap, Cn, Bp, Cn, Cn, acc);

#pragma unroll
  for (int it = 0; it < 4; it++)
#pragma unroll
    for (int jt = 0; jt < 4; jt++)
#pragma unroll
      for (int rr = 0; rr < 4; rr++){
        int o = ob*128 + wi*64 + it*16 + 4*g + rr;
        int n = nb*128 + wj*64 + jt*16 + r;
        out[((size_t)b * Cn + o) * Nn + n] = acc[it][jt][rr] + bout[o];
      }
}

extern "C" void kernel_launch(void* const* d_in, const int* in_sizes, int n_in,
                              void* d_out, int out_size, void* d_ws, size_t ws_size,
                              hipStream_t stream){
  const float* fmap  = (const float*)d_in[0];
  const float* Wqkvl = (const float*)d_in[1];
  const float* Wout  = (const float*)d_in[2];
  const float* bout  = (const float*)d_in[3];
  float* out = (float*)d_out;

  char* ws = (char*)d_ws;
  size_t off = 0;
  auto alloc = [&](size_t bytes) -> void* {
    void* p = ws + off;
    off += (bytes + 255) & ~(size_t)255;
    return p;
  };
  u16* W1bf  = (u16*)alloc((size_t)4*Cn*Cn*2);
  u16* Wobf  = (u16*)alloc((size_t)Cn*Cn*2);
  u16* fmapT = (u16*)alloc((size_t)Bn*Nn*Cn*2);
  u16* Qb    = (u16*)alloc((size_t)Bn*Nn*Cn*2);
  u16* Kb    = (u16*)alloc((size_t)Bn*Nn*Cn*2);
  u16* Lb    = (u16*)alloc((size_t)Bn*Nn*Cn*2);
  u16* Vt    = (u16*)alloc((size_t)Bn*Hn*Dn*Nn*2);
  u16* tok   = fmapT;   // fmapT dead after gemm1; reuse for attention output

  hipLaunchKernelGGL(k_convert, dim3((4*Cn*Cn/4 + 255)/256), dim3(256), 0, stream,
                     Wqkvl, W1bf, 4*Cn*Cn/4);
  hipLaunchKernelGGL(k_convert, dim3((Cn*Cn/4 + 255)/256), dim3(256), 0, stream,
                     Wout, Wobf, Cn*Cn/4);
  hipLaunchKernelGGL(k_transpose, dim3(Nn/32, Cn/32, Bn), dim3(256), 0, stream, fmap, fmapT);
  hipLaunchKernelGGL(k_gemm1, dim3(16, 8, Bn), dim3(256), 0, stream, fmapT, W1bf, Qb, Kb, Vt, Lb);
  hipLaunchKernelGGL(k_attn, dim3(1024), dim3(256), 0, stream, Qb, Kb, Vt, Lb, tok);
  hipLaunchKernelGGL(k_gemm2, dim3(4, 8, Bn), dim3(256), 0, stream, tok, Wobf, bout, out);
}